// Round 3
// baseline (29.814 us; speedup 1.0000x reference)
//
#include <hip/hip_runtime.h>
#include <float.h>
#include <math.h>

#define NB 32
#define LD 512
#define LP 4096
#define HD 128
#define PV 26
#define SP 32   // padded score-row stride (floats)
// ws layout: scores float[NB*LD*SP] @ 0  (2 MB)

// K1: scores panel  s[b,l,v] = d_feat[b,l] . prot_emb[v]
// 256 blocks x 512 threads. Wave q of 8 owns k in [q*16, q*16+16).
// A-sixteenth preloaded to 4 float4; B segment is wave-uniform -> scalar path.
__global__ __launch_bounds__(512) void k_scores(const int* __restrict__ drug_ids,
                                                const float* __restrict__ drug_emb,
                                                const float* __restrict__ prot_emb,
                                                float* __restrict__ scores) {
    int b = blockIdx.x >> 3;           // 8 row-chunks per batch
    int chunk = blockIdx.x & 7;
    int q = __builtin_amdgcn_readfirstlane(threadIdx.x >> 6);  // k-eighth, SGPR
    int lane = threadIdx.x & 63;
    int l = chunk * 64 + lane;

    const float* __restrict__ A =
        drug_emb + (size_t)drug_ids[b * LD + l] * HD + q * 16;
    float4 a[4];
    #pragma unroll
    for (int i = 0; i < 4; ++i) a[i] = reinterpret_cast<const float4*>(A)[i];

    const float* __restrict__ Bq = prot_emb + q * 16;
    float s[PV];
    #pragma unroll
    for (int v = 0; v < PV; ++v) s[v] = 0.f;

    #pragma unroll
    for (int i = 0; i < 4; ++i) {
        float4 av = a[i];
        #pragma unroll
        for (int v = 0; v < PV; ++v) {
            float4 p = reinterpret_cast<const float4*>(Bq + v * HD)[i];
            s[v] = fmaf(av.x, p.x, fmaf(av.y, p.y,
                   fmaf(av.z, p.z, fmaf(av.w, p.w, s[v]))));
        }
    }

    __shared__ float red[8][64][27];   // odd pad -> conflict-free
    #pragma unroll
    for (int v = 0; v < PV; ++v) red[q][lane][v] = s[v];
    __syncthreads();

    float* __restrict__ out = scores + ((size_t)b * LD + chunk * 64) * SP;
    for (int o = threadIdx.x; o < 64 * PV; o += 512) {
        int l2 = o / PV, v = o - l2 * PV;
        float sum = red[0][l2][v] + red[1][l2][v] + red[2][l2][v] + red[3][l2][v]
                  + red[4][l2][v] + red[5][l2][v] + red[6][l2][v] + red[7][l2][v];
        out[l2 * SP + v] = sum;
    }
}

// K2: fused tail. One block (1024 thr) per batch.
// hist -> mask/counts; masked rowmax + drug softmax; colmax from panel;
// protein softmax via counts; d_vec gather; p_vec; 256->64->1 MLP.
__global__ __launch_bounds__(1024) void k_tail(const int* __restrict__ drug_ids,
                                               const int* __restrict__ prot_ids,
                                               const float* __restrict__ drug_emb,
                                               const float* __restrict__ prot_emb,
                                               const float* __restrict__ scores,
                                               const float* __restrict__ W1,
                                               const float* __restrict__ b1,
                                               const float* __restrict__ W2,
                                               const float* __restrict__ b2,
                                               float* __restrict__ out) {
    int b = blockIdx.x;
    int t = threadIdx.x;
    int wid = t >> 6, lane = t & 63;

    __shared__ int   cnt4[4][PV];
    __shared__ int   scnt[PV];
    __shared__ unsigned smask;
    __shared__ int   sids[LD];
    __shared__ float att[LD];
    __shared__ float redm[8], reds[8];
    __shared__ float cpart[8][PV];
    __shared__ float ew[PV];
    __shared__ float sInvP;
    __shared__ float comb[2 * HD];
    __shared__ float part[8][HD];
    __shared__ float hpart[4][64];

    // Phase 0: histogram of prot_ids (one int4 per thread) + drug ids to LDS
    if (t < 4 * PV) ((int*)cnt4)[t] = 0;
    if (t < LD) sids[t] = drug_ids[b * LD + t];
    __syncthreads();
    {
        int4 v = reinterpret_cast<const int4*>(prot_ids + b * LP)[t];
        int sub = wid & 3;
        atomicAdd(&cnt4[sub][v.x], 1);
        atomicAdd(&cnt4[sub][v.y], 1);
        atomicAdd(&cnt4[sub][v.z], 1);
        atomicAdd(&cnt4[sub][v.w], 1);
    }
    __syncthreads();
    if (t < 64) {
        int c = 0;
        if (t < PV) {
            c = cnt4[0][t] + cnt4[1][t] + cnt4[2][t] + cnt4[3][t];
            scnt[t] = c;
        }
        unsigned long long bal = __ballot(c > 0);
        if (t == 0) smask = (unsigned)bal;
    }
    __syncthreads();
    unsigned msk = smask;

    // Phase 1: load score panel row, masked rowmax, drug softmax numerators
    float sc[PV];
    float r = -FLT_MAX;
    if (t < LD) {
        const float4* srow =
            reinterpret_cast<const float4*>(scores + ((size_t)b * LD + t) * SP);
        float4 f0 = srow[0], f1 = srow[1], f2 = srow[2], f3 = srow[3],
               f4 = srow[4], f5 = srow[5], f6 = srow[6];
        sc[0]=f0.x; sc[1]=f0.y; sc[2]=f0.z; sc[3]=f0.w;
        sc[4]=f1.x; sc[5]=f1.y; sc[6]=f1.z; sc[7]=f1.w;
        sc[8]=f2.x; sc[9]=f2.y; sc[10]=f2.z; sc[11]=f2.w;
        sc[12]=f3.x; sc[13]=f3.y; sc[14]=f3.z; sc[15]=f3.w;
        sc[16]=f4.x; sc[17]=f4.y; sc[18]=f4.z; sc[19]=f4.w;
        sc[20]=f5.x; sc[21]=f5.y; sc[22]=f5.z; sc[23]=f5.w;
        sc[24]=f6.x; sc[25]=f6.y;
        #pragma unroll
        for (int v = 0; v < PV; ++v)
            if ((msk >> v) & 1) r = fmaxf(r, sc[v]);
        float m = r;
        #pragma unroll
        for (int off = 32; off; off >>= 1) m = fmaxf(m, __shfl_xor(m, off, 64));
        if (lane == 0) redm[wid] = m;
    }
    __syncthreads();
    float gm = fmaxf(fmaxf(fmaxf(redm[0], redm[1]), fmaxf(redm[2], redm[3])),
                     fmaxf(fmaxf(redm[4], redm[5]), fmaxf(redm[6], redm[7])));
    if (t < LD) {
        float e = __expf(r - gm);
        att[t] = e;
        float ssum = e;
        #pragma unroll
        for (int off = 32; off; off >>= 1) ssum += __shfl_xor(ssum, off, 64);
        if (lane == 0) reds[wid] = ssum;

        // Phase 2: per-wave colmax partials (64 rows each)
        #pragma unroll
        for (int v = 0; v < PV; ++v) {
            float cm = sc[v];
            #pragma unroll
            for (int off = 32; off; off >>= 1)
                cm = fmaxf(cm, __shfl_xor(cm, off, 64));
            if (lane == 0) cpart[wid][v] = cm;
        }
    }
    __syncthreads();
    float invD = 1.f / (reds[0] + reds[1] + reds[2] + reds[3] +
                        reds[4] + reds[5] + reds[6] + reds[7]);

    // Phase 3: protein softmax weights (wave 0, all 64 lanes in shfl)
    if (wid == 0) {
        float cm = -FLT_MAX;
        if (lane < PV) {
            #pragma unroll
            for (int q = 0; q < 8; ++q) cm = fmaxf(cm, cpart[q][lane]);
            if (!((msk >> lane) & 1)) cm = -FLT_MAX;
        }
        float M = cm;
        #pragma unroll
        for (int off = 32; off; off >>= 1) M = fmaxf(M, __shfl_xor(M, off, 64));
        int c = (lane < PV) ? scnt[lane] : 0;
        float w = (c > 0) ? (float)c * __expf(cm - M) : 0.f;
        float S = w;
        #pragma unroll
        for (int off = 32; off; off >>= 1) S += __shfl_xor(S, off, 64);
        if (lane < PV) ew[lane] = w;
        if (lane == 0) sInvP = 1.f / S;
    }
    __syncthreads();

    // Phase 4: d_vec partials — 8 groups of 64 rows, 128 h each
    {
        int h = t & 127, g = t >> 7;
        float acc = 0.f;
        #pragma unroll 8
        for (int i = 0; i < 64; ++i) {
            int l = g * 64 + i;
            acc = fmaf(att[l], drug_emb[(size_t)sids[l] * HD + h], acc);
        }
        part[g][h] = acc;
    }
    __syncthreads();

    // Phase 5: combined = [d_vec | p_vec]
    if (t < HD) {
        float d = part[0][t] + part[1][t] + part[2][t] + part[3][t] +
                  part[4][t] + part[5][t] + part[6][t] + part[7][t];
        comb[t] = d * invD;
    } else if (t < 2 * HD) {
        int h = t - HD;
        float acc = 0.f;
        #pragma unroll
        for (int v = 0; v < PV; ++v)
            acc = fmaf(ew[v], prot_emb[v * HD + h], acc);
        comb[t] = acc * sInvP;
    }
    __syncthreads();

    // MLP: layer 1 with 4-way K split, then layer 2
    if (t < 256) {
        int j = t & 63, seg = t >> 6;
        float acc = 0.f;
        #pragma unroll
        for (int k = 0; k < 64; ++k) {
            int kk = seg * 64 + k;
            acc = fmaf(comb[kk], W1[kk * 64 + j], acc);
        }
        hpart[seg][j] = acc;
    }
    __syncthreads();
    if (t < 64) {
        float hj = b1[t] + hpart[0][t] + hpart[1][t] + hpart[2][t] + hpart[3][t];
        hj = fmaxf(hj, 0.f);
        float o = hj * W2[t];
        #pragma unroll
        for (int off = 32; off; off >>= 1) o += __shfl_xor(o, off, 64);
        if (t == 0) out[b] = o + b2[0];
    }
}

extern "C" void kernel_launch(void* const* d_in, const int* in_sizes, int n_in,
                              void* d_out, int out_size, void* d_ws, size_t ws_size,
                              hipStream_t stream) {
    const int*   drug_ids = (const int*)d_in[0];
    const int*   prot_ids = (const int*)d_in[1];
    const float* drug_emb = (const float*)d_in[2];
    const float* prot_emb = (const float*)d_in[3];
    const float* W1 = (const float*)d_in[4];
    const float* b1 = (const float*)d_in[5];
    const float* W2 = (const float*)d_in[6];
    const float* b2 = (const float*)d_in[7];
    float* out = (float*)d_out;

    float* scores = (float*)d_ws;   // NB*LD*SP floats = 2 MB

    k_scores<<<NB * 8, 512, 0, stream>>>(drug_ids, drug_emb, prot_emb, scores);
    k_tail<<<NB, 1024, 0, stream>>>(drug_ids, prot_ids, drug_emb, prot_emb,
                                    scores, W1, b1, W2, b2, out);
}

// Round 4
// 18.419 us; speedup vs baseline: 1.6187x; 1.6187x over previous
//
#include <hip/hip_runtime.h>
#include <float.h>
#include <math.h>

#define NB 32
#define LD 512
#define LP 4096
#define HD 128
#define PV 26
// ws layout (floats):
//   rowmax  float[NB*LD]      @ 0       (65536 B)
//   colpart float[NB*8*32]    @ 16384   (32768 B)  [chunk-level col maxima, padded]

// K1: per (batch, 64-row chunk): scores = d_feat . prot_emb^T with 8-way
// K-split; emits masked row-max and per-chunk col-max. No atomics, no deps.
__global__ __launch_bounds__(512) void k_scores(const int* __restrict__ drug_ids,
                                                const int* __restrict__ prot_ids,
                                                const float* __restrict__ drug_emb,
                                                const float* __restrict__ prot_emb,
                                                float* __restrict__ rowmax,
                                                float* __restrict__ colpart) {
    int b = blockIdx.x >> 3;           // 8 row-chunks per batch
    int chunk = blockIdx.x & 7;
    int t = threadIdx.x;
    int q = __builtin_amdgcn_readfirstlane(t >> 6);  // k-eighth, SGPR
    int lane = t & 63;
    int l = chunk * 64 + lane;

    __shared__ float red[8][64][27];   // 55.3 KB, odd pad -> 2-way max
    __shared__ unsigned wor[8];

    // presence mask: 4096 ids, 8 per thread, OR-reduce
    const int4* pid4 = reinterpret_cast<const int4*>(prot_ids + b * LP);
    int4 i0 = pid4[t], i1 = pid4[t + 512];
    unsigned pm = (1u << i0.x) | (1u << i0.y) | (1u << i0.z) | (1u << i0.w)
                | (1u << i1.x) | (1u << i1.y) | (1u << i1.z) | (1u << i1.w);
    #pragma unroll
    for (int off = 32; off; off >>= 1) pm |= __shfl_xor(pm, off, 64);
    if (lane == 0) wor[q] = pm;

    // A sixteenth-row preload (16 k-floats)
    const float* __restrict__ A =
        drug_emb + (size_t)drug_ids[b * LD + l] * HD + q * 16;
    float4 a[4];
    #pragma unroll
    for (int i = 0; i < 4; ++i) a[i] = reinterpret_cast<const float4*>(A)[i];

    const float* __restrict__ Bq = prot_emb + q * 16;
    float s[PV];
    #pragma unroll
    for (int v = 0; v < PV; ++v) s[v] = 0.f;

    #pragma unroll
    for (int i = 0; i < 4; ++i) {
        float4 av = a[i];
        #pragma unroll
        for (int v = 0; v < PV; ++v) {
            float4 p = reinterpret_cast<const float4*>(Bq + v * HD)[i];
            s[v] = fmaf(av.x, p.x, fmaf(av.y, p.y,
                   fmaf(av.z, p.z, fmaf(av.w, p.w, s[v]))));
        }
    }

    #pragma unroll
    for (int v = 0; v < PV; ++v) red[q][lane][v] = s[v];
    __syncthreads();

    unsigned msk = wor[0] | wor[1] | wor[2] | wor[3]
                 | wor[4] | wor[5] | wor[6] | wor[7];

    // sum the 8 k-slices (each (l2,v) owned by exactly one thread)
    for (int o = t; o < 64 * PV; o += 512) {
        int l2 = o / PV, v = o - l2 * PV;
        float sum = red[0][l2][v] + red[1][l2][v] + red[2][l2][v] + red[3][l2][v]
                  + red[4][l2][v] + red[5][l2][v] + red[6][l2][v] + red[7][l2][v];
        red[0][l2][v] = sum;
    }
    __syncthreads();

    if (t < 64) {
        float m = -FLT_MAX;
        #pragma unroll
        for (int v = 0; v < PV; ++v)
            if ((msk >> v) & 1) m = fmaxf(m, red[0][t][v]);
        rowmax[b * LD + chunk * 64 + t] = m;
    } else if (t < 64 + PV) {
        int v = t - 64;
        float m = -FLT_MAX;
        for (int r = 0; r < 64; ++r) m = fmaxf(m, red[0][r][v]);
        colpart[((b << 3) + chunk) * 32 + v] = m;
    }
}

// K2: fused tail. One block (1024 thr) per batch.
__global__ __launch_bounds__(1024) void k_tail(const int* __restrict__ drug_ids,
                                               const int* __restrict__ prot_ids,
                                               const float* __restrict__ drug_emb,
                                               const float* __restrict__ prot_emb,
                                               const float* __restrict__ rowmax,
                                               const float* __restrict__ colpart,
                                               const float* __restrict__ W1,
                                               const float* __restrict__ b1,
                                               const float* __restrict__ W2,
                                               const float* __restrict__ b2,
                                               float* __restrict__ out) {
    int b = blockIdx.x;
    int t = threadIdx.x;
    int wid = t >> 6, lane = t & 63;

    __shared__ int   cnt4[4][PV];
    __shared__ int   scnt[PV];
    __shared__ int   sids[LD];
    __shared__ float att[LD];
    __shared__ float redm[8], reds[8];
    __shared__ float ew[PV];
    __shared__ float sInvP;
    __shared__ float comb[2 * HD];
    __shared__ float part[8][HD];
    __shared__ float hpart[4][64];

    // Phase 0: issue loads early; histogram of prot_ids (1 int4/thread)
    float r = -FLT_MAX;
    if (t < LD) {
        sids[t] = drug_ids[b * LD + t];
        r = rowmax[b * LD + t];
    }
    float cm = -FLT_MAX;
    if (t >= LD && t < LD + PV) {            // wave 8: col maxima
        int v = t - LD;
        #pragma unroll
        for (int c = 0; c < 8; ++c)
            cm = fmaxf(cm, colpart[((b << 3) + c) * 32 + v]);
    }
    if (t < 4 * PV) ((int*)cnt4)[t] = 0;
    __syncthreads();
    {
        int4 v = reinterpret_cast<const int4*>(prot_ids + b * LP)[t];
        int sub = wid & 3;
        atomicAdd(&cnt4[sub][v.x], 1);
        atomicAdd(&cnt4[sub][v.y], 1);
        atomicAdd(&cnt4[sub][v.z], 1);
        atomicAdd(&cnt4[sub][v.w], 1);
    }
    // drug row-max block reduction (overlaps hist completion)
    if (t < LD) {
        float m = r;
        #pragma unroll
        for (int off = 32; off; off >>= 1) m = fmaxf(m, __shfl_xor(m, off, 64));
        if (lane == 0) redm[wid] = m;
    }
    __syncthreads();
    if (t < PV) scnt[t] = cnt4[0][t] + cnt4[1][t] + cnt4[2][t] + cnt4[3][t];
    float gm = fmaxf(fmaxf(fmaxf(redm[0], redm[1]), fmaxf(redm[2], redm[3])),
                     fmaxf(fmaxf(redm[4], redm[5]), fmaxf(redm[6], redm[7])));
    if (t < LD) {
        float e = __expf(r - gm);
        att[t] = e;
        float ssum = e;
        #pragma unroll
        for (int off = 32; off; off >>= 1) ssum += __shfl_xor(ssum, off, 64);
        if (lane == 0) reds[wid] = ssum;
    }
    __syncthreads();
    float invD = 1.f / (reds[0] + reds[1] + reds[2] + reds[3] +
                        reds[4] + reds[5] + reds[6] + reds[7]);

    // Phase 1: protein softmax weights (wave 8, lanes 0..25 hold cm)
    if (wid == 8) {
        int c = (lane < PV) ? scnt[lane] : 0;
        float m0 = (c > 0) ? cm : -FLT_MAX;
        float M = m0;
        #pragma unroll
        for (int off = 32; off; off >>= 1) M = fmaxf(M, __shfl_xor(M, off, 64));
        float w = (c > 0) ? (float)c * __expf(cm - M) : 0.f;
        float S = w;
        #pragma unroll
        for (int off = 32; off; off >>= 1) S += __shfl_xor(S, off, 64);
        if (lane < PV) ew[lane] = w;
        if (lane == 0) sInvP = 1.f / S;
    }

    // Phase 2: d_vec partials — 8 groups of 64 rows, 128 h each
    {
        int h = t & 127, g = t >> 7;
        float acc = 0.f;
        #pragma unroll 8
        for (int i = 0; i < 64; ++i) {
            int l = g * 64 + i;
            acc = fmaf(att[l], drug_emb[(size_t)sids[l] * HD + h], acc);
        }
        part[g][h] = acc;
    }
    __syncthreads();

    // Phase 3: combined = [d_vec | p_vec]
    if (t < HD) {
        float d = part[0][t] + part[1][t] + part[2][t] + part[3][t] +
                  part[4][t] + part[5][t] + part[6][t] + part[7][t];
        comb[t] = d * invD;
    } else if (t < 2 * HD) {
        int h = t - HD;
        float acc = 0.f;
        #pragma unroll
        for (int v = 0; v < PV; ++v)
            acc = fmaf(ew[v], prot_emb[v * HD + h], acc);
        comb[t] = acc * sInvP;
    }
    __syncthreads();

    // Phase 4: MLP 256->64 (4-way K split) -> relu -> 64->1
    if (t < 256) {
        int j = t & 63, seg = t >> 6;
        float acc = 0.f;
        #pragma unroll
        for (int k = 0; k < 64; ++k) {
            int kk = seg * 64 + k;
            acc = fmaf(comb[kk], W1[kk * 64 + j], acc);
        }
        hpart[seg][j] = acc;
    }
    __syncthreads();
    if (t < 64) {
        float hj = b1[t] + hpart[0][t] + hpart[1][t] + hpart[2][t] + hpart[3][t];
        hj = fmaxf(hj, 0.f);
        float o = hj * W2[t];
        #pragma unroll
        for (int off = 32; off; off >>= 1) o += __shfl_xor(o, off, 64);
        if (t == 0) out[b] = o + b2[0];
    }
}

extern "C" void kernel_launch(void* const* d_in, const int* in_sizes, int n_in,
                              void* d_out, int out_size, void* d_ws, size_t ws_size,
                              hipStream_t stream) {
    const int*   drug_ids = (const int*)d_in[0];
    const int*   prot_ids = (const int*)d_in[1];
    const float* drug_emb = (const float*)d_in[2];
    const float* prot_emb = (const float*)d_in[3];
    const float* W1 = (const float*)d_in[4];
    const float* b1 = (const float*)d_in[5];
    const float* W2 = (const float*)d_in[6];
    const float* b2 = (const float*)d_in[7];
    float* out = (float*)d_out;

    char* ws = (char*)d_ws;
    float* rowmax  = (float*)(ws + 0);
    float* colpart = (float*)(ws + 65536);

    k_scores<<<NB * 8, 512, 0, stream>>>(drug_ids, prot_ids, drug_emb, prot_emb,
                                         rowmax, colpart);
    k_tail<<<NB, 1024, 0, stream>>>(drug_ids, prot_ids, drug_emb, prot_emb,
                                    rowmax, colpart, W1, b1, W2, b2, out);
}